// Round 14
// baseline (115.547 us; speedup 1.0000x reference)
//
#include <hip/hip_runtime.h>

#define B 64
#define S 32
#define V 50000
#define E 300
#define H 16
#define D 16
#define M 256   // H*D
#define AH 200
#define AHH 100 // e-half
#define BS 2048 // B*S

#define C2 2.88539008177793f       // 2*log2(e): exp2(C2*x) = e^{2x}
#define LOG2E 1.44269504088896f    // log2(e)

#if __has_builtin(__builtin_amdgcn_exp2f)
#define EXP2(x) __builtin_amdgcn_exp2f(x)
#else
#define EXP2(x) __builtin_exp2f(x)
#endif

// ---------------- K1: embed gather + proj + fused QKV (R13, stable) ----------
// grid 256 blocks x 1024 threads; block = 8 rows.
__global__ __launch_bounds__(1024) void k1_embed_qkv(
    const int* __restrict__ x, const float* __restrict__ emb,
    const float* __restrict__ W_proj, const float* __restrict__ b_proj,
    const float* __restrict__ Wq, const float* __restrict__ bq,
    const float* __restrict__ Wk, const float* __restrict__ bk,
    const float* __restrict__ Wv, const float* __restrict__ bv,
    float* __restrict__ q, float* __restrict__ k, float* __restrict__ v)
{
    __shared__ float embl[8][E];        // 9.6 KB
    __shared__ float hl[8][M];          // 8 KB
    __shared__ float part[8][8][M];     // 64 KB
    __shared__ int idxl[8];
    const int tid = threadIdx.x;
    const int col2 = (tid & 127) * 2;
    const int grp = tid >> 7;           // 0..7
    const int r0 = blockIdx.x * 8;
    const int rr = tid >> 7;
    const int rc2 = (tid & 127) * 2;

    if (tid < 8) idxl[tid] = x[r0 + tid];
    __syncthreads();
    for (int t = tid; t < 8 * E; t += 1024) {
        int r = t / E, e = t % E;
        embl[r][e] = emb[(long)idxl[r] * E + e];
    }
    __syncthreads();

    // ---- phase A: proj, all 8 groups (6x38 + 2x36 = 300) ----
    {
        const int e0 = (grp < 6) ? 38 * grp : 228 + 36 * (grp - 6);
        const int ecnt = (grp < 6) ? 38 : 36;
        float2 acc[8];
#pragma unroll
        for (int r = 0; r < 8; r++) acc[r] = make_float2(0.f, 0.f);
#pragma unroll 2
        for (int e = e0; e < e0 + ecnt; e += 2) {
            float2 w0 = *reinterpret_cast<const float2*>(&W_proj[e * M + col2]);
            float2 w1 = *reinterpret_cast<const float2*>(&W_proj[(e + 1) * M + col2]);
#pragma unroll
            for (int r = 0; r < 8; r++) {
                float2 hm = *reinterpret_cast<const float2*>(&embl[r][e]);
                acc[r].x += hm.x * w0.x; acc[r].y += hm.x * w0.y;
                acc[r].x += hm.y * w1.x; acc[r].y += hm.y * w1.y;
            }
        }
#pragma unroll
        for (int r = 0; r < 8; r++)
            *reinterpret_cast<float2*>(&part[grp][r][col2]) = acc[r];
    }
    __syncthreads();
    {
        float2 s = *reinterpret_cast<const float2*>(&b_proj[rc2]);
#pragma unroll
        for (int g = 0; g < 8; g++) {
            float2 p = *reinterpret_cast<const float2*>(&part[g][rr][rc2]);
            s.x += p.x; s.y += p.y;
        }
        *reinterpret_cast<float2*>(&hl[rr][rc2]) = s;
    }
    __syncthreads();

    // ---- phase B: fused QKV (8 groups x 32 k's), unroll 2 ----
    float2 aq[8], ak[8], av[8];
#pragma unroll
    for (int r = 0; r < 8; r++) {
        aq[r] = make_float2(0.f, 0.f);
        ak[r] = make_float2(0.f, 0.f);
        av[r] = make_float2(0.f, 0.f);
    }
    {
        const int cb = 32 * grp;
#pragma unroll 2
        for (int c = cb; c < cb + 32; c += 2) {
            float2 wq0 = *reinterpret_cast<const float2*>(&Wq[c * M + col2]);
            float2 wk0 = *reinterpret_cast<const float2*>(&Wk[c * M + col2]);
            float2 wv0 = *reinterpret_cast<const float2*>(&Wv[c * M + col2]);
            float2 wq1 = *reinterpret_cast<const float2*>(&Wq[(c + 1) * M + col2]);
            float2 wk1 = *reinterpret_cast<const float2*>(&Wk[(c + 1) * M + col2]);
            float2 wv1 = *reinterpret_cast<const float2*>(&Wv[(c + 1) * M + col2]);
#pragma unroll
            for (int r = 0; r < 8; r++) {
                float2 hm = *reinterpret_cast<const float2*>(&hl[r][c]);
                aq[r].x += hm.x * wq0.x; aq[r].y += hm.x * wq0.y;
                ak[r].x += hm.x * wk0.x; ak[r].y += hm.x * wk0.y;
                av[r].x += hm.x * wv0.x; av[r].y += hm.x * wv0.y;
                aq[r].x += hm.y * wq1.x; aq[r].y += hm.y * wq1.y;
                ak[r].x += hm.y * wk1.x; ak[r].y += hm.y * wk1.y;
                av[r].x += hm.y * wv1.x; av[r].y += hm.y * wv1.y;
            }
        }
    }
#pragma unroll
    for (int r = 0; r < 8; r++)
        *reinterpret_cast<float2*>(&part[grp][r][col2]) = aq[r];
    __syncthreads();
    {
        float2 s = *reinterpret_cast<const float2*>(&bq[rc2]);
#pragma unroll
        for (int g = 0; g < 8; g++) {
            float2 p = *reinterpret_cast<const float2*>(&part[g][rr][rc2]);
            s.x += p.x; s.y += p.y;
        }
        *reinterpret_cast<float2*>(&q[(r0 + rr) * M + rc2]) = s;
    }
    __syncthreads();
#pragma unroll
    for (int r = 0; r < 8; r++)
        *reinterpret_cast<float2*>(&part[grp][r][col2]) = ak[r];
    __syncthreads();
    {
        float2 s = *reinterpret_cast<const float2*>(&bk[rc2]);
#pragma unroll
        for (int g = 0; g < 8; g++) {
            float2 p = *reinterpret_cast<const float2*>(&part[g][rr][rc2]);
            s.x += p.x; s.y += p.y;
        }
        *reinterpret_cast<float2*>(&k[(r0 + rr) * M + rc2]) = s;
    }
    __syncthreads();
#pragma unroll
    for (int r = 0; r < 8; r++)
        *reinterpret_cast<float2*>(&part[grp][r][col2]) = av[r];
    __syncthreads();
    {
        float2 s = *reinterpret_cast<const float2*>(&bv[rc2]);
#pragma unroll
        for (int g = 0; g < 8; g++) {
            float2 p = *reinterpret_cast<const float2*>(&part[g][rr][rc2]);
            s.x += p.x; s.y += p.y;
        }
        *reinterpret_cast<float2*>(&v[(r0 + rr) * M + rc2]) = s;
    }
}

// ---------------- K2: partial additive-attention scores ----------------
// grid B*H*2 = 2048 blocks x 512 threads; block -> (b, h, e-half)
// Emits RAW partial scores: -2 * sum_{e in half} av_e / (1 + Eq*Ek).
// Phase 2: thread -> (i = tid>>4, jq=(tid>>1)&7 -> 4 j's, es = tid&1).
// b128 j-contiguous Ekt reads: 6 LDS reads per 16 terms (R6: ~10 eq-b64).
// unroll 1 + pointer-increment addressing (R6 discipline); live set ~40
// regs -> no spill at (512,8)'s 64-VGPR cap. Odd 25-chunk count splits
// 13/12 across the es lane-pair (benign divergence).
// Banks: Ekt b128 @ stride 34 -> 16 addrs cover all 32 banks 2-way (free);
// Eq b128 @ 104i+4es -> all 32 banks once; avl broadcast (free).
#define EQS 104  // Eq stride (16B-aligned rows)
#define EKS 34   // Ekt stride (8B-aligned rows)
__global__ __launch_bounds__(512, 8) void k2_scores(
    const float* __restrict__ q, const float* __restrict__ k,
    const float* __restrict__ W_attn, const float* __restrict__ b_attn,
    const float* __restrict__ attn_v, float* __restrict__ psc)
{
    __shared__ __align__(16) float ql[S][D];        // 2 KB
    __shared__ __align__(16) float kl[S][D];        // 2 KB
    __shared__ __align__(16) float Eqs[S][EQS];     // 13.3 KB
    __shared__ __align__(16) float Ekts[AHH][EKS];  // 13.6 KB
    __shared__ __align__(16) float avl[AHH];        // 0.4 KB
    const int tid = threadIdx.x;
    const int eh = blockIdx.x & 1;
    const int h = (blockIdx.x >> 1) & 15;
    const int b = blockIdx.x >> 5;
    const int e0g = eh * AHH;

    ql[tid >> 4][tid & 15] = q[(b * S + (tid >> 4)) * M + h * D + (tid & 15)];
    kl[tid >> 4][tid & 15] = k[(b * S + (tid >> 4)) * M + h * D + (tid & 15)];
    if (tid < AHH) avl[tid] = attn_v[e0g + tid];
    __syncthreads();

    // phase 1: pg 0/1 -> Eq (i-halves), pg 2/3 -> Ekt (j-halves); e in half
    {
        const int e = tid & 127;
        const int pg = tid >> 7;
        if (e < AHH) {
            const int eg = e0g + e;
            if (pg < 2) {
                float w1c[D];
#pragma unroll
                for (int d = 0; d < D; d++) w1c[d] = W_attn[d * AH + eg];
                float be = b_attn[eg];
                const int i0 = pg * 16;
                for (int i = i0; i < i0 + 16; i++) {
                    float a1 = be;
                    const float4* qr = reinterpret_cast<const float4*>(&ql[i][0]);
#pragma unroll
                    for (int dq = 0; dq < 4; dq++) {
                        float4 qv = qr[dq];
                        a1 += qv.x * w1c[4 * dq] + qv.y * w1c[4 * dq + 1]
                            + qv.z * w1c[4 * dq + 2] + qv.w * w1c[4 * dq + 3];
                    }
                    Eqs[i][e] = EXP2(C2 * a1);
                }
            } else {
                float w2c[D];
#pragma unroll
                for (int d = 0; d < D; d++) w2c[d] = W_attn[(D + d) * AH + eg];
                const int j0i = (pg - 2) * 16;
                for (int j = j0i; j < j0i + 16; j++) {
                    float a2 = 0.f;
                    const float4* kr = reinterpret_cast<const float4*>(&kl[j][0]);
#pragma unroll
                    for (int dq = 0; dq < 4; dq++) {
                        float4 kv = kr[dq];
                        a2 += kv.x * w2c[4 * dq] + kv.y * w2c[4 * dq + 1]
                            + kv.z * w2c[4 * dq + 2] + kv.w * w2c[4 * dq + 3];
                    }
                    Ekts[e][j] = EXP2(C2 * a2);
                }
            }
        }
    }
    __syncthreads();

    // phase 2: 4e x 4j chunks; es lane-parity strides the 25 chunks
    const int i = tid >> 4;
    const int jq = (tid >> 1) & 7;
    const int es = tid & 1;
    const int j0 = 4 * jq;
    float acc0 = 0.f, acc1 = 0.f, acc2 = 0.f, acc3 = 0.f;
    const float* eqp = &Eqs[i][4 * es];
    const float* avp = &avl[4 * es];
    const float* ekp = &Ekts[4 * es][j0];

#pragma unroll 1
    for (int ec = es; ec < AHH / 4; ec += 2) {
        float4 eq  = *reinterpret_cast<const float4*>(eqp);
        float4 avv = *reinterpret_cast<const float4*>(avp);
        float4 k0  = *reinterpret_cast<const float4*>(ekp);
        float4 k1  = *reinterpret_cast<const float4*>(ekp + EKS);
        float4 k2v = *reinterpret_cast<const float4*>(ekp + 2 * EKS);
        float4 k3v = *reinterpret_cast<const float4*>(ekp + 3 * EKS);
        // RAT4 over the 4 e's for each j (k-row component j)
#define RAT4(c0, c1, c2, c3, accv)                                            \
        {                                                                     \
            float a0 = 1.f + eq.x * (c0), a1 = 1.f + eq.y * (c1);             \
            float a2 = 1.f + eq.z * (c2), a3 = 1.f + eq.w * (c3);             \
            float p01 = a0 * a1, p23 = a2 * a3;                               \
            float t01 = avv.x * a1 + avv.y * a0;                              \
            float t23 = avv.z * a3 + avv.w * a2;                              \
            float num = t01 * p23 + t23 * p01;                                \
            accv += num * __builtin_amdgcn_rcpf(p01 * p23);                   \
        }
        RAT4(k0.x, k1.x, k2v.x, k3v.x, acc0)
        RAT4(k0.y, k1.y, k2v.y, k3v.y, acc1)
        RAT4(k0.z, k1.z, k2v.z, k3v.z, acc2)
        RAT4(k0.w, k1.w, k2v.w, k3v.w, acc3)
#undef RAT4
        eqp += 8; avp += 8; ekp += 8 * EKS;
    }

    // combine the two e-parities (lane pair); es==0 stores float4
    acc0 += __shfl_xor(acc0, 1, 64);
    acc1 += __shfl_xor(acc1, 1, 64);
    acc2 += __shfl_xor(acc2, 1, 64);
    acc3 += __shfl_xor(acc3, 1, 64);
    if (es == 0) {
        float* po = psc + (size_t)eh * (B * H * S * S);
        float4 o = make_float4(-2.f * acc0, -2.f * acc1,
                               -2.f * acc2, -2.f * acc3);
        *reinterpret_cast<float4*>(
            &po[((b * H + h) * S + i) * S + j0]) = o;
    }
}

// ---------------- K3: combine halves + softmax + ctx + FC + partial max ----
// grid B*4 = 256 blocks x 1024 threads; block -> (b, ig) with 8 i's
__global__ __launch_bounds__(1024) void k3_ctx_fc(
    const float* __restrict__ v, const float* __restrict__ psc,
    const float* __restrict__ W_fc, const float* __restrict__ b_fc,
    float* __restrict__ part_out)
{
    __shared__ float vl[8][H][D];                   // 8 KB
    __shared__ __align__(16) float wl[H][8][S];     // 16 KB
    __shared__ float ctxl[8][S * D];                // 16 KB
    __shared__ float pfc[4][8][M];                  // 32 KB
    const int tid = threadIdx.x;
    const int b = blockIdx.x >> 2, ig = blockIdx.x & 3;
    const float* psc0 = psc;
    const float* psc1 = psc + (size_t)(B * H * S * S);

    for (int t = tid; t < 8 * M; t += 1024) {
        int i = t >> 8, md = t & 255;
        vl[i][md >> 4][md & 15] = v[(b * S + ig * 8 + i) * M + md];
    }
    for (int t = tid; t < H * 8 * S; t += 1024) {
        int h = t >> 8, r = t & 255;
        int i = r >> 5, j = r & 31;
        int idx = ((b * H + h) * S + (ig * 8 + i)) * S + j;
        wl[h][i][j] = psc0[idx] + psc1[idx];
    }
    __syncthreads();

    // softmax over j: 128 rows (h, i), 8 threads/row, 4 j's each
    {
        const int row = tid >> 3;               // 0..127
        const int h = row >> 3, il = row & 7;
        const int jq = (tid & 7) * 4;
        float4 sv = *reinterpret_cast<const float4*>(&wl[h][il][jq]);
        float mx = fmaxf(fmaxf(sv.x, sv.y), fmaxf(sv.z, sv.w));
#pragma unroll
        for (int msk = 1; msk < 8; msk <<= 1) mx = fmaxf(mx, __shfl_xor(mx, msk, 64));
        float p0 = EXP2(LOG2E * (sv.x - mx));
        float p1 = EXP2(LOG2E * (sv.y - mx));
        float p2 = EXP2(LOG2E * (sv.z - mx));
        float p3 = EXP2(LOG2E * (sv.w - mx));
        float ps = p0 + p1 + p2 + p3;
#pragma unroll
        for (int msk = 1; msk < 8; msk <<= 1) ps += __shfl_xor(ps, msk, 64);
        float rs = __builtin_amdgcn_rcpf(ps);
        float4 wv = make_float4(p0 * rs, p1 * rs, p2 * rs, p3 * rs);
        *reinterpret_cast<float4*>(&wl[h][il][jq]) = wv;
    }
    __syncthreads();

    for (int t = tid; t < 8 * S * D; t += 1024) {
        int i = t >> 9, jd = t & 511;
        int j = jd >> 4, d = jd & 15;
        float a = 0.f;
#pragma unroll
        for (int h = 0; h < H; h++) a += wl[h][i][j] * vl[i][h][d];
        ctxl[i][j * D + d] = a;
    }
    __syncthreads();

    const int col = tid & 255, grp = tid >> 8;
    {
        float acc[8];
#pragma unroll
        for (int ii = 0; ii < 8; ii++) acc[ii] = 0.f;
        const int e0 = 128 * grp;
#pragma unroll 4
        for (int e = e0; e < e0 + 128; e++) {
            float wf = W_fc[e * M + col];
#pragma unroll
            for (int ii = 0; ii < 8; ii++) acc[ii] += ctxl[ii][e] * wf;
        }
#pragma unroll
        for (int ii = 0; ii < 8; ii++) pfc[grp][ii][col] = acc[ii];
    }
    __syncthreads();
    if (tid < 256) {
        float bf = b_fc[tid];
        float mxv = -3.4e38f;
#pragma unroll
        for (int ii = 0; ii < 8; ii++) {
            float s = pfc[0][ii][tid] + pfc[1][ii][tid] + pfc[2][ii][tid]
                    + pfc[3][ii][tid] + bf;
            mxv = fmaxf(mxv, s);
        }
        part_out[(b * 4 + ig) * M + tid] = mxv;
    }
}

// ---------------- K4: final max over the 4 i-groups ----------------
__global__ __launch_bounds__(256) void k4_max(
    const float* __restrict__ part, float* __restrict__ out)
{
    const int b = blockIdx.x, m = threadIdx.x;
    float v0 = part[(b * 4 + 0) * M + m];
    float v1 = part[(b * 4 + 1) * M + m];
    float v2 = part[(b * 4 + 2) * M + m];
    float v3 = part[(b * 4 + 3) * M + m];
    out[b * M + m] = fmaxf(fmaxf(v0, v1), fmaxf(v2, v3));
}

extern "C" void kernel_launch(void* const* d_in, const int* in_sizes, int n_in,
                              void* d_out, int out_size, void* d_ws, size_t ws_size,
                              hipStream_t stream) {
    const int*   x      = (const int*)  d_in[0];
    const float* emb    = (const float*)d_in[1];
    const float* W_proj = (const float*)d_in[2];
    const float* b_proj = (const float*)d_in[3];
    const float* Wq     = (const float*)d_in[4];
    const float* bq     = (const float*)d_in[5];
    const float* Wk     = (const float*)d_in[6];
    const float* bk     = (const float*)d_in[7];
    const float* Wv     = (const float*)d_in[8];
    const float* bv     = (const float*)d_in[9];
    const float* W_attn = (const float*)d_in[10];
    const float* b_attn = (const float*)d_in[11];
    const float* attn_v = (const float*)d_in[12];
    const float* W_fc   = (const float*)d_in[13];
    const float* b_fc   = (const float*)d_in[14];
    float* out = (float*)d_out;

    float* ws   = (float*)d_ws;
    float* q    = ws;                        // BS*M
    float* k    = q + BS * M;                // BS*M
    float* v    = k + BS * M;                // BS*M
    float* psc  = v + BS * M;                // 2 * B*H*S*S
    float* part = psc + 2 * B * H * S * S;   // B*4*M

    k1_embed_qkv<<<BS / 8, 1024, 0, stream>>>(x, emb, W_proj, b_proj,
                                              Wq, bq, Wk, bk, Wv, bv, q, k, v);
    k2_scores<<<B * H * 2, 512, 0, stream>>>(q, k, W_attn, b_attn, attn_v, psc);
    k3_ctx_fc<<<B * 4, 1024, 0, stream>>>(v, psc, W_fc, b_fc, part);
    k4_max<<<B, 256, 0, stream>>>(part, out);
}

// Round 15
// 80.346 us; speedup vs baseline: 1.4381x; 1.4381x over previous
//
#include <hip/hip_runtime.h>

#define B 64
#define S 32
#define V 50000
#define E 300
#define H 16
#define D 16
#define M 256   // H*D
#define AH 200
#define AHH 100 // e-half
#define BS 2048 // B*S

#define C2 2.88539008177793f       // 2*log2(e): exp2(C2*x) = e^{2x}
#define LOG2E 1.44269504088896f    // log2(e)

#if __has_builtin(__builtin_amdgcn_exp2f)
#define EXP2(x) __builtin_amdgcn_exp2f(x)
#else
#define EXP2(x) __builtin_exp2f(x)
#endif

// ---------------- K1: embed gather + proj + fused QKV (R13, stable) ----------
// grid 256 blocks x 1024 threads; block = 8 rows.
__global__ __launch_bounds__(1024) void k1_embed_qkv(
    const int* __restrict__ x, const float* __restrict__ emb,
    const float* __restrict__ W_proj, const float* __restrict__ b_proj,
    const float* __restrict__ Wq, const float* __restrict__ bq,
    const float* __restrict__ Wk, const float* __restrict__ bk,
    const float* __restrict__ Wv, const float* __restrict__ bv,
    float* __restrict__ q, float* __restrict__ k, float* __restrict__ v)
{
    __shared__ float embl[8][E];        // 9.6 KB
    __shared__ float hl[8][M];          // 8 KB
    __shared__ float part[8][8][M];     // 64 KB
    __shared__ int idxl[8];
    const int tid = threadIdx.x;
    const int col2 = (tid & 127) * 2;
    const int grp = tid >> 7;           // 0..7
    const int r0 = blockIdx.x * 8;
    const int rr = tid >> 7;
    const int rc2 = (tid & 127) * 2;

    if (tid < 8) idxl[tid] = x[r0 + tid];
    __syncthreads();
    for (int t = tid; t < 8 * E; t += 1024) {
        int r = t / E, e = t % E;
        embl[r][e] = emb[(long)idxl[r] * E + e];
    }
    __syncthreads();

    // ---- phase A: proj, all 8 groups (6x38 + 2x36 = 300) ----
    {
        const int e0 = (grp < 6) ? 38 * grp : 228 + 36 * (grp - 6);
        const int ecnt = (grp < 6) ? 38 : 36;
        float2 acc[8];
#pragma unroll
        for (int r = 0; r < 8; r++) acc[r] = make_float2(0.f, 0.f);
#pragma unroll 2
        for (int e = e0; e < e0 + ecnt; e += 2) {
            float2 w0 = *reinterpret_cast<const float2*>(&W_proj[e * M + col2]);
            float2 w1 = *reinterpret_cast<const float2*>(&W_proj[(e + 1) * M + col2]);
#pragma unroll
            for (int r = 0; r < 8; r++) {
                float2 hm = *reinterpret_cast<const float2*>(&embl[r][e]);
                acc[r].x += hm.x * w0.x; acc[r].y += hm.x * w0.y;
                acc[r].x += hm.y * w1.x; acc[r].y += hm.y * w1.y;
            }
        }
#pragma unroll
        for (int r = 0; r < 8; r++)
            *reinterpret_cast<float2*>(&part[grp][r][col2]) = acc[r];
    }
    __syncthreads();
    {
        float2 s = *reinterpret_cast<const float2*>(&b_proj[rc2]);
#pragma unroll
        for (int g = 0; g < 8; g++) {
            float2 p = *reinterpret_cast<const float2*>(&part[g][rr][rc2]);
            s.x += p.x; s.y += p.y;
        }
        *reinterpret_cast<float2*>(&hl[rr][rc2]) = s;
    }
    __syncthreads();

    // ---- phase B: fused QKV (8 groups x 32 k's), unroll 2 ----
    float2 aq[8], ak[8], av[8];
#pragma unroll
    for (int r = 0; r < 8; r++) {
        aq[r] = make_float2(0.f, 0.f);
        ak[r] = make_float2(0.f, 0.f);
        av[r] = make_float2(0.f, 0.f);
    }
    {
        const int cb = 32 * grp;
#pragma unroll 2
        for (int c = cb; c < cb + 32; c += 2) {
            float2 wq0 = *reinterpret_cast<const float2*>(&Wq[c * M + col2]);
            float2 wk0 = *reinterpret_cast<const float2*>(&Wk[c * M + col2]);
            float2 wv0 = *reinterpret_cast<const float2*>(&Wv[c * M + col2]);
            float2 wq1 = *reinterpret_cast<const float2*>(&Wq[(c + 1) * M + col2]);
            float2 wk1 = *reinterpret_cast<const float2*>(&Wk[(c + 1) * M + col2]);
            float2 wv1 = *reinterpret_cast<const float2*>(&Wv[(c + 1) * M + col2]);
#pragma unroll
            for (int r = 0; r < 8; r++) {
                float2 hm = *reinterpret_cast<const float2*>(&hl[r][c]);
                aq[r].x += hm.x * wq0.x; aq[r].y += hm.x * wq0.y;
                ak[r].x += hm.x * wk0.x; ak[r].y += hm.x * wk0.y;
                av[r].x += hm.x * wv0.x; av[r].y += hm.x * wv0.y;
                aq[r].x += hm.y * wq1.x; aq[r].y += hm.y * wq1.y;
                ak[r].x += hm.y * wk1.x; ak[r].y += hm.y * wk1.y;
                av[r].x += hm.y * wv1.x; av[r].y += hm.y * wv1.y;
            }
        }
    }
#pragma unroll
    for (int r = 0; r < 8; r++)
        *reinterpret_cast<float2*>(&part[grp][r][col2]) = aq[r];
    __syncthreads();
    {
        float2 s = *reinterpret_cast<const float2*>(&bq[rc2]);
#pragma unroll
        for (int g = 0; g < 8; g++) {
            float2 p = *reinterpret_cast<const float2*>(&part[g][rr][rc2]);
            s.x += p.x; s.y += p.y;
        }
        *reinterpret_cast<float2*>(&q[(r0 + rr) * M + rc2]) = s;
    }
    __syncthreads();
#pragma unroll
    for (int r = 0; r < 8; r++)
        *reinterpret_cast<float2*>(&part[grp][r][col2]) = ak[r];
    __syncthreads();
    {
        float2 s = *reinterpret_cast<const float2*>(&bk[rc2]);
#pragma unroll
        for (int g = 0; g < 8; g++) {
            float2 p = *reinterpret_cast<const float2*>(&part[g][rr][rc2]);
            s.x += p.x; s.y += p.y;
        }
        *reinterpret_cast<float2*>(&k[(r0 + rr) * M + rc2]) = s;
    }
    __syncthreads();
#pragma unroll
    for (int r = 0; r < 8; r++)
        *reinterpret_cast<float2*>(&part[grp][r][col2]) = av[r];
    __syncthreads();
    {
        float2 s = *reinterpret_cast<const float2*>(&bv[rc2]);
#pragma unroll
        for (int g = 0; g < 8; g++) {
            float2 p = *reinterpret_cast<const float2*>(&part[g][rr][rc2]);
            s.x += p.x; s.y += p.y;
        }
        *reinterpret_cast<float2*>(&v[(r0 + rr) * M + rc2]) = s;
    }
}

// ---------------- K2: partial additive-attention scores (R6, LOCKED) ----
// grid B*H*2 = 2048 blocks x 512 threads; block -> (b, h, e-half)
// Emits RAW partial scores: -2 * sum_{e in half} av_e / (1 + Eq*Ek).
// Best-measured variant: 42.7 us, VGPR 32, zero bank conflicts. Do not touch.
#define EQS 104  // Eq stride (16B-aligned rows)
#define EKS 34   // Ekt stride (8B-aligned rows, conflict-free b64 reads)
__global__ __launch_bounds__(512, 8) void k2_scores(
    const float* __restrict__ q, const float* __restrict__ k,
    const float* __restrict__ W_attn, const float* __restrict__ b_attn,
    const float* __restrict__ attn_v, float* __restrict__ psc)
{
    __shared__ __align__(16) float ql[S][D];        // 2 KB
    __shared__ __align__(16) float kl[S][D];        // 2 KB
    __shared__ __align__(16) float Eqs[S][EQS];     // 13.3 KB
    __shared__ __align__(16) float Ekts[AHH][EKS];  // 13.6 KB
    const int tid = threadIdx.x;
    const int eh = blockIdx.x & 1;
    const int h = (blockIdx.x >> 1) & 15;
    const int b = blockIdx.x >> 5;
    const int e0g = eh * AHH;

    ql[tid >> 4][tid & 15] = q[(b * S + (tid >> 4)) * M + h * D + (tid & 15)];
    kl[tid >> 4][tid & 15] = k[(b * S + (tid >> 4)) * M + h * D + (tid & 15)];
    __syncthreads();

    // phase 1: pg 0/1 -> Eq (i-halves), pg 2/3 -> Ekt (j-halves); e in half
    {
        const int e = tid & 127;
        const int pg = tid >> 7;
        if (e < AHH) {
            const int eg = e0g + e;
            if (pg < 2) {
                float w1c[D];
#pragma unroll
                for (int d = 0; d < D; d++) w1c[d] = W_attn[d * AH + eg];
                float be = b_attn[eg];
                const int i0 = pg * 16;
                for (int i = i0; i < i0 + 16; i++) {
                    float a1 = be;
                    const float4* qr = reinterpret_cast<const float4*>(&ql[i][0]);
#pragma unroll
                    for (int dq = 0; dq < 4; dq++) {
                        float4 qv = qr[dq];
                        a1 += qv.x * w1c[4 * dq] + qv.y * w1c[4 * dq + 1]
                            + qv.z * w1c[4 * dq + 2] + qv.w * w1c[4 * dq + 3];
                    }
                    Eqs[i][e] = EXP2(C2 * a1);
                }
            } else {
                float w2c[D];
#pragma unroll
                for (int d = 0; d < D; d++) w2c[d] = W_attn[(D + d) * AH + eg];
                const int j0i = (pg - 2) * 16;
                for (int j = j0i; j < j0i + 16; j++) {
                    float a2 = 0.f;
                    const float4* kr = reinterpret_cast<const float4*>(&kl[j][0]);
#pragma unroll
                    for (int dq = 0; dq < 4; dq++) {
                        float4 kv = kr[dq];
                        a2 += kv.x * w2c[4 * dq] + kv.y * w2c[4 * dq + 1]
                            + kv.z * w2c[4 * dq + 2] + kv.w * w2c[4 * dq + 3];
                    }
                    Ekts[e][j] = EXP2(C2 * a2);
                }
            }
        }
    }
    __syncthreads();

    // phase 2: thread -> (i = tid>>4, j = 2*(tid&15)+{0,1}); 25 x 4-e chunks
    const int i = tid >> 4;
    const int j0 = tid & 15;
    float acc0 = 0.f, acc1 = 0.f;
    const float4* avp = reinterpret_cast<const float4*>(attn_v + e0g);
#pragma unroll 1
    for (int ec = 0; ec < AHH / 4; ec++) {
        float4 eq = *reinterpret_cast<const float4*>(&Eqs[i][4 * ec]);
        float4 avv = avp[ec];
        float2 e0 = *reinterpret_cast<const float2*>(&Ekts[4 * ec + 0][2 * j0]);
        float2 e1 = *reinterpret_cast<const float2*>(&Ekts[4 * ec + 1][2 * j0]);
        float2 e2 = *reinterpret_cast<const float2*>(&Ekts[4 * ec + 2][2 * j0]);
        float2 e3 = *reinterpret_cast<const float2*>(&Ekts[4 * ec + 3][2 * j0]);
        {
            float a0 = 1.f + eq.x * e0.x, a1 = 1.f + eq.y * e1.x;
            float a2 = 1.f + eq.z * e2.x, a3 = 1.f + eq.w * e3.x;
            float p01 = a0 * a1, p23 = a2 * a3;
            float t01 = avv.x * a1 + avv.y * a0;
            float t23 = avv.z * a3 + avv.w * a2;
            float num = t01 * p23 + t23 * p01;
            acc0 += num * __builtin_amdgcn_rcpf(p01 * p23);
        }
        {
            float a0 = 1.f + eq.x * e0.y, a1 = 1.f + eq.y * e1.y;
            float a2 = 1.f + eq.z * e2.y, a3 = 1.f + eq.w * e3.y;
            float p01 = a0 * a1, p23 = a2 * a3;
            float t01 = avv.x * a1 + avv.y * a0;
            float t23 = avv.z * a3 + avv.w * a2;
            float num = t01 * p23 + t23 * p01;
            acc1 += num * __builtin_amdgcn_rcpf(p01 * p23);
        }
    }
    float2 out2 = make_float2(-2.f * acc0, -2.f * acc1);
    float* po = psc + (size_t)eh * (B * H * S * S);
    *reinterpret_cast<float2*>(&po[((b * H + h) * S + i) * S + 2 * j0]) = out2;
}

// ---------------- K3: combine halves + softmax + ctx + FC + partial max ----
// grid B*4 = 256 blocks x 1024 threads; block -> (b, ig) with 8 i's
// FC vectorized: 8 groups x 128 threads, float2 W_fc loads (512B/wave
// coalesced), 64 e's/group; acc 16 regs (live ~25: no spill risk).
__global__ __launch_bounds__(1024) void k3_ctx_fc(
    const float* __restrict__ v, const float* __restrict__ psc,
    const float* __restrict__ W_fc, const float* __restrict__ b_fc,
    float* __restrict__ part_out)
{
    __shared__ float vl[8][H][D];                   // 8 KB
    __shared__ __align__(16) float wl[H][8][S];     // 16 KB
    __shared__ float ctxl[8][S * D];                // 16 KB
    __shared__ float pfc8[8][8][M];                 // 64 KB
    __shared__ float sred[8][M];                    // 8 KB  (112 KB total)
    const int tid = threadIdx.x;
    const int b = blockIdx.x >> 2, ig = blockIdx.x & 3;
    const float* psc0 = psc;
    const float* psc1 = psc + (size_t)(B * H * S * S);

    for (int t = tid; t < 8 * M; t += 1024) {
        int i = t >> 8, md = t & 255;
        vl[i][md >> 4][md & 15] = v[(b * S + ig * 8 + i) * M + md];
    }
    for (int t = tid; t < H * 8 * S; t += 1024) {
        int h = t >> 8, r = t & 255;
        int i = r >> 5, j = r & 31;
        int idx = ((b * H + h) * S + (ig * 8 + i)) * S + j;
        wl[h][i][j] = psc0[idx] + psc1[idx];
    }
    __syncthreads();

    // softmax over j: 128 rows (h, i), 8 threads/row, 4 j's each
    {
        const int row = tid >> 3;               // 0..127
        const int h = row >> 3, il = row & 7;
        const int jq = (tid & 7) * 4;
        float4 sv = *reinterpret_cast<const float4*>(&wl[h][il][jq]);
        float mx = fmaxf(fmaxf(sv.x, sv.y), fmaxf(sv.z, sv.w));
#pragma unroll
        for (int msk = 1; msk < 8; msk <<= 1) mx = fmaxf(mx, __shfl_xor(mx, msk, 64));
        float p0 = EXP2(LOG2E * (sv.x - mx));
        float p1 = EXP2(LOG2E * (sv.y - mx));
        float p2 = EXP2(LOG2E * (sv.z - mx));
        float p3 = EXP2(LOG2E * (sv.w - mx));
        float ps = p0 + p1 + p2 + p3;
#pragma unroll
        for (int msk = 1; msk < 8; msk <<= 1) ps += __shfl_xor(ps, msk, 64);
        float rs = __builtin_amdgcn_rcpf(ps);
        float4 wv = make_float4(p0 * rs, p1 * rs, p2 * rs, p3 * rs);
        *reinterpret_cast<float4*>(&wl[h][il][jq]) = wv;
    }
    __syncthreads();

    for (int t = tid; t < 8 * S * D; t += 1024) {
        int i = t >> 9, jd = t & 511;
        int j = jd >> 4, d = jd & 15;
        float a = 0.f;
#pragma unroll
        for (int h = 0; h < H; h++) a += wl[h][i][j] * vl[i][h][d];
        ctxl[i][j * D + d] = a;
    }
    __syncthreads();

    // FC: 8 groups x 128 threads; thread -> 2 cols; 64 e's per group
    const int col2f = (tid & 127) * 2;
    const int g8 = tid >> 7;
    {
        float2 acc[8];
#pragma unroll
        for (int ii = 0; ii < 8; ii++) acc[ii] = make_float2(0.f, 0.f);
        const int e0 = 64 * g8;
#pragma unroll 2
        for (int e = e0; e < e0 + 64; e++) {
            float2 wf = *reinterpret_cast<const float2*>(&W_fc[e * M + col2f]);
#pragma unroll
            for (int ii = 0; ii < 8; ii++) {
                float c = ctxl[ii][e];
                acc[ii].x += c * wf.x;
                acc[ii].y += c * wf.y;
            }
        }
#pragma unroll
        for (int ii = 0; ii < 8; ii++)
            *reinterpret_cast<float2*>(&pfc8[g8][ii][col2f]) = acc[ii];
    }
    __syncthreads();
    // reduce the 8 partials: 1024 threads -> (ii = tid>>7, col-pair)
    {
        const int ii = tid >> 7;
        float2 s = *reinterpret_cast<const float2*>(&b_fc[col2f]);
#pragma unroll
        for (int g = 0; g < 8; g++) {
            float2 p = *reinterpret_cast<const float2*>(&pfc8[g][ii][col2f]);
            s.x += p.x; s.y += p.y;
        }
        *reinterpret_cast<float2*>(&sred[ii][col2f]) = s;
    }
    __syncthreads();
    // max over the 8 i's per column
    if (tid < 256) {
        float mxv = sred[0][tid];
#pragma unroll
        for (int ii = 1; ii < 8; ii++) mxv = fmaxf(mxv, sred[ii][tid]);
        part_out[(b * 4 + ig) * M + tid] = mxv;
    }
}

// ---------------- K4: final max over the 4 i-groups ----------------
__global__ __launch_bounds__(256) void k4_max(
    const float* __restrict__ part, float* __restrict__ out)
{
    const int b = blockIdx.x, m = threadIdx.x;
    float v0 = part[(b * 4 + 0) * M + m];
    float v1 = part[(b * 4 + 1) * M + m];
    float v2 = part[(b * 4 + 2) * M + m];
    float v3 = part[(b * 4 + 3) * M + m];
    out[b * M + m] = fmaxf(fmaxf(v0, v1), fmaxf(v2, v3));
}

extern "C" void kernel_launch(void* const* d_in, const int* in_sizes, int n_in,
                              void* d_out, int out_size, void* d_ws, size_t ws_size,
                              hipStream_t stream) {
    const int*   x      = (const int*)  d_in[0];
    const float* emb    = (const float*)d_in[1];
    const float* W_proj = (const float*)d_in[2];
    const float* b_proj = (const float*)d_in[3];
    const float* Wq     = (const float*)d_in[4];
    const float* bq     = (const float*)d_in[5];
    const float* Wk     = (const float*)d_in[6];
    const float* bk     = (const float*)d_in[7];
    const float* Wv     = (const float*)d_in[8];
    const float* bv     = (const float*)d_in[9];
    const float* W_attn = (const float*)d_in[10];
    const float* b_attn = (const float*)d_in[11];
    const float* attn_v = (const float*)d_in[12];
    const float* W_fc   = (const float*)d_in[13];
    const float* b_fc   = (const float*)d_in[14];
    float* out = (float*)d_out;

    float* ws   = (float*)d_ws;
    float* q    = ws;                        // BS*M
    float* k    = q + BS * M;                // BS*M
    float* v    = k + BS * M;                // BS*M
    float* psc  = v + BS * M;                // 2 * B*H*S*S
    float* part = psc + 2 * B * H * S * S;   // B*4*M

    k1_embed_qkv<<<BS / 8, 1024, 0, stream>>>(x, emb, W_proj, b_proj,
                                              Wq, bq, Wk, bk, Wv, bv, q, k, v);
    k2_scores<<<B * H * 2, 512, 0, stream>>>(q, k, W_attn, b_attn, attn_v, psc);
    k3_ctx_fc<<<B * 4, 1024, 0, stream>>>(v, psc, W_fc, b_fc, part);
    k4_max<<<B, 256, 0, stream>>>(part, out);
}